// Round 6
// baseline (250.329 us; speedup 1.0000x reference)
//
#include <hip/hip_runtime.h>
#include <hip/hip_bf16.h>
#include <math.h>

#define B_TOT 16384
#define NPART 16
#define NPAIR 120     // 16*15/2
#define HID   64
#define DL    5
#define STRIDE 72     // ushorts per LDS row (64 + 8 pad) = 144 B, 16B-aligned
#define PHI_BASE 128  // psi rows [0,128), phi rows [128,144)

typedef __attribute__((ext_vector_type(8))) short short8;
typedef __attribute__((ext_vector_type(4))) float floatx4;

// v * sigmoid(1.702 v): 1 trans exp + 1 trans rcp. Max abs dev from exact GELU
// ~0.02 << error budget (0.79 threshold, bf16-quantized compare).
__device__ __forceinline__ float gelu_sig(float v) {
    float e = __expf(-1.702f * v);
    return v * __builtin_amdgcn_rcpf(1.0f + e);
}

// pack two f32 -> packed bf16 (v_cvt_pk_bf16_f32), a -> low half
__device__ __forceinline__ unsigned pk2(float a, float b) {
    __hip_bfloat162 h = __float22bfloat162_rn(make_float2(a, b));
    union { __hip_bfloat162 h; unsigned u; } cv; cv.h = h;
    return cv.u;
}

__device__ __forceinline__ float wred(float v) {
    v += __shfl_down(v, 32);
    v += __shfl_down(v, 16);
    v += __shfl_down(v, 8);
    v += __shfl_down(v, 4);
    v += __shfl_down(v, 2);
    v += __shfl_down(v, 1);
    return v;
}

// Block = 1 batch element, 256 threads (4 waves). LDS ~21 KB -> 7 blocks/CU
// (vs 41 KB/3 blocks at GB=2): occupancy is the lever this round.
// Layer-2 via MFMA 16x16x32 bf16 (wave wv owns output cols wv*16..+15);
// layer-3 folded into in-register column sums (row-mean commutes with matmul).
__global__ __launch_bounds__(256) void jastrow_mfma3(
    const float* __restrict__ x,
    const float* __restrict__ phi_w0, const float* __restrict__ phi_b0,
    const float* __restrict__ phi_w1, const float* __restrict__ phi_b1,
    const float* __restrict__ phi_w2, const float* __restrict__ phi_b2,
    const float* __restrict__ psi_w0, const float* __restrict__ psi_b0,
    const float* __restrict__ psi_w1, const float* __restrict__ psi_b1,
    const float* __restrict__ psi_w2, const float* __restrict__ psi_b2,
    const float* __restrict__ rho_w0, const float* __restrict__ rho_b0,
    const float* __restrict__ rho_w1, const float* __restrict__ rho_b1,
    float* __restrict__ out)
{
    const int t    = threadIdx.x;
    const int lane = t & 63;
    const int wv   = t >> 6;
    const int b    = blockIdx.x;

    __shared__ __align__(16) unsigned short s_h[(128 + NPART) * STRIDE];
    __shared__ float s_red[4][12];   // [wave][ psi·w2 (5) | phi·w2 (5) | cusp ]

    const float2* x2 = (const float2*)x;
    float cusp = 0.f;

    // ============ Phase 1a: psi features + layer 1 -> h1 bf16 in LDS ============
    if (t < 128) {
        const int p = t;
        const int rowbase = p * STRIDE;
        if (p < NPAIR) {
            // closed-form triu decode (exact: sqrt of odd perfect squares <=961)
            int u = 119 - p;
            float s = sqrtf((float)(8 * u + 1));
            int k = (int)((s - 1.0f) * 0.5f);
            int i = 14 - k;
            int j = p - (i * (31 - i)) / 2 + i + 1;

            float2 xi = x2[b * NPART + i];
            float2 xj = x2[b * NPART + j];
            float dx = xi.x - xj.x, dy = xi.y - xj.y;
            float r = sqrtf(dx * dx + dy * dy + 1e-12f);

            float f0 = __logf(1.f + r);
            float f1 = r * __builtin_amdgcn_rcpf(1.f + r);
            float f2 = __expf(-r * r);
            float f3 = __expf(-0.5f * r);
            float f4 = __expf(-r);
            float f5 = f4 * f4;
            cusp = r * f4;            // exact fp32

#pragma unroll
            for (int ch = 0; ch < 8; ++ch) {
                union { short8 s; unsigned u[4]; } v;
#pragma unroll
                for (int e2 = 0; e2 < 4; ++e2) {
                    int jj = ch * 8 + e2 * 2;
                    const float* w = psi_w0 + jj * 6;
                    float a0 = psi_b0[jj]     + f0 * w[0]  + f1 * w[1]  + f2 * w[2]
                                              + f3 * w[3]  + f4 * w[4]  + f5 * w[5];
                    float a1 = psi_b0[jj + 1] + f0 * w[6]  + f1 * w[7]  + f2 * w[8]
                                              + f3 * w[9]  + f4 * w[10] + f5 * w[11];
                    v.u[e2] = pk2(gelu_sig(a0), gelu_sig(a1));
                }
                *(short8*)&s_h[rowbase + ch * 8] = v.s;
            }
        } else {
            short8 z = (short8)0;
#pragma unroll
            for (int ch = 0; ch < 8; ++ch) *(short8*)&s_h[rowbase + ch * 8] = z;
        }
    } else {
        // ============ Phase 1b: phi layer 1, 8 units/thread (128 threads) =======
        int tt = t - 128;
        int prow = tt >> 3;            // 0..15
        int seg  = tt & 7;
        float2 xv = x2[b * NPART + prow];
        float r2 = xv.x * xv.x + xv.y * xv.y;
        union { short8 s; unsigned u[4]; } v;
#pragma unroll
        for (int e2 = 0; e2 < 4; ++e2) {
            int jj = seg * 8 + e2 * 2;
            const float* w = phi_w0 + jj * 3;
            float a0 = phi_b0[jj]     + xv.x * w[0] + xv.y * w[1] + r2 * w[2];
            float a1 = phi_b0[jj + 1] + xv.x * w[3] + xv.y * w[4] + r2 * w[5];
            v.u[e2] = pk2(gelu_sig(a0), gelu_sig(a1));
        }
        *(short8*)&s_h[(PHI_BASE + prow) * STRIDE + seg * 8] = v.s;
    }
    __syncthreads();

    // ============ Phase 2: layer 2 via MFMA 16x16x32 bf16 ======================
    const int m15  = lane & 15;
    const int q    = lane >> 4;
    const int colb = wv * 16 + m15;        // this lane's output column

    short8 Bpsi[2], Bphi[2];
#pragma unroll
    for (int Kc = 0; Kc < 2; ++Kc) {
        int k0 = Kc * 32 + q * 8;
        const float* wp = psi_w1 + colb * HID + k0;
        const float* wf = phi_w1 + colb * HID + k0;
        union { short8 s; unsigned u[4]; } bp, bf;
#pragma unroll
        for (int e2 = 0; e2 < 4; ++e2) {
            bp.u[e2] = pk2(wp[e2 * 2], wp[e2 * 2 + 1]);
            bf.u[e2] = pk2(wf[e2 * 2], wf[e2 * 2 + 1]);
        }
        Bpsi[Kc] = bp.s; Bphi[Kc] = bf.s;
    }

    floatx4 accP[8];
    floatx4 accF;
#pragma unroll
    for (int Mt = 0; Mt < 8; ++Mt) accP[Mt] = (floatx4)0.f;
    accF = (floatx4)0.f;

#pragma unroll
    for (int Mt = 0; Mt < 8; ++Mt) {
        int ab = (Mt * 16 + m15) * STRIDE + q * 8;
        short8 a0 = *(const short8*)&s_h[ab];
        short8 a1 = *(const short8*)&s_h[ab + 32];
        accP[Mt] = __builtin_amdgcn_mfma_f32_16x16x32_bf16(a0, Bpsi[0], accP[Mt], 0, 0, 0);
        accP[Mt] = __builtin_amdgcn_mfma_f32_16x16x32_bf16(a1, Bpsi[1], accP[Mt], 0, 0, 0);
    }
    {
        int ab = (PHI_BASE + m15) * STRIDE + q * 8;
        short8 a0 = *(const short8*)&s_h[ab];
        short8 a1 = *(const short8*)&s_h[ab + 32];
        accF = __builtin_amdgcn_mfma_f32_16x16x32_bf16(a0, Bphi[0], accF, 0, 0, 0);
        accF = __builtin_amdgcn_mfma_f32_16x16x32_bf16(a1, Bphi[1], accF, 0, 0, 0);
    }

    // ============ Phase 3: gelu + in-register column sums (no h2 LDS) ==========
    // D layout: row = q*4+rg, col = colb. out[d] = (1/R) sum_k colsum[k] w2[d,k] + b2[d]
    float red[11];
    {
        float biasP = psi_b1[colb];
        float biasF = phi_b1[colb];
        float cs = 0.f;
#pragma unroll
        for (int Mt = 0; Mt < 8; ++Mt) {
            if (Mt == 7) {
                if (q < 2) {   // rows 120..127 are zero-pad -> exclude
#pragma unroll
                    for (int rg = 0; rg < 4; ++rg)
                        cs += gelu_sig(accP[Mt][rg] + biasP);
                }
            } else {
#pragma unroll
                for (int rg = 0; rg < 4; ++rg)
                    cs += gelu_sig(accP[Mt][rg] + biasP);
            }
        }
#pragma unroll
        for (int d = 0; d < DL; ++d)
            red[d] = cs * psi_w2[d * HID + colb];

        float cf = 0.f;
#pragma unroll
        for (int rg = 0; rg < 4; ++rg)
            cf += gelu_sig(accF[rg] + biasF);
#pragma unroll
        for (int d = 0; d < DL; ++d)
            red[DL + d] = cf * phi_w2[d * HID + colb];
        red[10] = cusp;
    }

#pragma unroll
    for (int v = 0; v < 11; ++v) {
        float s = wred(red[v]);
        if (lane == 0) s_red[wv][v] = s;
    }
    __syncthreads();

    // ============ Phase 4: rho readout on wave 0 ===============================
    if (t < 64) {
        int j = t;
        float a = rho_b0[j];
        const float* wr = rho_w0 + j * (2 * DL);
#pragma unroll
        for (int d = 0; d < DL; ++d) {
            float psiv = (s_red[0][d] + s_red[1][d] + s_red[2][d] + s_red[3][d])
                         * (1.0f / NPAIR) + psi_b2[d];
            float phiv = (s_red[0][DL + d] + s_red[1][DL + d] + s_red[2][DL + d] + s_red[3][DL + d])
                         * (1.0f / NPART) + phi_b2[d];
            a += phiv * wr[d] + psiv * wr[DL + d];
        }
        float cuspb = s_red[0][10] + s_red[1][10];   // waves 2,3 carry no cusp
        float c = gelu_sig(a) * rho_w1[j];
        c = wred(c);
        if (j == 0) out[b] = c + rho_b1[0] + cuspb;
    }
}

extern "C" void kernel_launch(void* const* d_in, const int* in_sizes, int n_in,
                              void* d_out, int out_size, void* d_ws, size_t ws_size,
                              hipStream_t stream) {
    const float* x      = (const float*)d_in[0];
    const float* phi_w0 = (const float*)d_in[1];
    const float* phi_b0 = (const float*)d_in[2];
    const float* phi_w1 = (const float*)d_in[3];
    const float* phi_b1 = (const float*)d_in[4];
    const float* phi_w2 = (const float*)d_in[5];
    const float* phi_b2 = (const float*)d_in[6];
    const float* psi_w0 = (const float*)d_in[7];
    const float* psi_b0 = (const float*)d_in[8];
    const float* psi_w1 = (const float*)d_in[9];
    const float* psi_b1 = (const float*)d_in[10];
    const float* psi_w2 = (const float*)d_in[11];
    const float* psi_b2 = (const float*)d_in[12];
    const float* rho_w0 = (const float*)d_in[13];
    const float* rho_b0 = (const float*)d_in[14];
    const float* rho_w1 = (const float*)d_in[15];
    const float* rho_b1 = (const float*)d_in[16];

    jastrow_mfma3<<<B_TOT, 256, 0, stream>>>(
        x,
        phi_w0, phi_b0, phi_w1, phi_b1, phi_w2, phi_b2,
        psi_w0, psi_b0, psi_w1, psi_b1, psi_w2, psi_b2,
        rho_w0, rho_b0, rho_w1, rho_b1,
        (float*)d_out);
}

// Round 7
// 205.047 us; speedup vs baseline: 1.2208x; 1.2208x over previous
//
#include <hip/hip_runtime.h>
#include <hip/hip_bf16.h>
#include <math.h>

#define B_TOT 16384
#define NPART 16
#define NPAIR 120     // 16*15/2
#define HID   64
#define DL    5
#define GB    2       // batch elements per block
#define STRIDE 72     // ushorts per h1 LDS row (64 + 8 pad) = 144 B
#define PHI_ROW 256   // h1/feature row index where phi rows start
#define NROW  288     // 256 psi rows (incl. 8 pad/batch) + 32 phi rows

typedef __attribute__((ext_vector_type(8))) short short8;
typedef __attribute__((ext_vector_type(4))) float floatx4;

// v * sigmoid(1.702 v): 1 trans exp + 1 trans rcp; ~0.02 max dev from exact GELU
__device__ __forceinline__ float gelu_sig(float v) {
    float e = __expf(-1.702f * v);
    return v * __builtin_amdgcn_rcpf(1.0f + e);
}

// pack two f32 -> packed bf16 (v_cvt_pk_bf16_f32), a -> low half
__device__ __forceinline__ unsigned pk2(float a, float b) {
    __hip_bfloat162 h = __float22bfloat162_rn(make_float2(a, b));
    union { __hip_bfloat162 h; unsigned u; } cv; cv.h = h;
    return cv.u;
}

__device__ __forceinline__ unsigned short f2bfbits(float f) {
    __hip_bfloat16 h = __float2bfloat16(f);
    union { __hip_bfloat16 h; unsigned short u; } cv; cv.h = h;
    return cv.u;
}

__device__ __forceinline__ float wred(float v) {
    v += __shfl_down(v, 32);
    v += __shfl_down(v, 16);
    v += __shfl_down(v, 8);
    v += __shfl_down(v, 4);
    v += __shfl_down(v, 2);
    v += __shfl_down(v, 1);
    return v;
}

// Block = 2 batch elements, 256 threads (4 waves).
// Phase 0: features -> bf16 LDS rows (K padded to 8).
// Phase 1: layer-1 via MFMA 16x16x32 (only q==0 k-slots nonzero) + gelu
//          + b16 scatter into h1 (A-layout for layer-2).
// Phase 2+3 fused: layer-2 MFMA per tile + gelu + in-register column sums
//          (layer-3 folded: row-mean commutes with matmul).
// Phase 4: 2 readout waves do the 10 length-64 dots + rho. Cusp exact fp32.
__global__ __launch_bounds__(256) void jastrow_mfma4(
    const float* __restrict__ x,
    const float* __restrict__ phi_w0, const float* __restrict__ phi_b0,
    const float* __restrict__ phi_w1, const float* __restrict__ phi_b1,
    const float* __restrict__ phi_w2, const float* __restrict__ phi_b2,
    const float* __restrict__ psi_w0, const float* __restrict__ psi_b0,
    const float* __restrict__ psi_w1, const float* __restrict__ psi_b1,
    const float* __restrict__ psi_w2, const float* __restrict__ psi_b2,
    const float* __restrict__ rho_w0, const float* __restrict__ rho_b0,
    const float* __restrict__ rho_w1, const float* __restrict__ rho_b1,
    float* __restrict__ out)
{
    const int t    = threadIdx.x;
    const int lane = t & 63;
    const int wv   = t >> 6;
    const int q    = lane >> 4;
    const int m15  = lane & 15;
    const int bg   = blockIdx.x * GB;

    __shared__ __align__(16) unsigned short s_f[NROW * 8];        // features, 16B/row
    __shared__ __align__(16) unsigned short s_h[NROW * STRIDE];   // h1 bf16
    __shared__ float s_csP[GB][4][4][16];   // psi colsum partials [bl][wv][q][m15]
    __shared__ float s_csF[GB][4][4][16];   // phi colsum partials
    __shared__ float s_cusp[4];

    const float2* x2 = (const float2*)x;
    float cusp = 0.f;

    // ================= Phase 0: features -> s_f ================================
    {
        const int bl = t >> 7;
        const int p  = t & 127;
        union { short8 s; unsigned u[4]; } v;
        v.s = (short8)0;
        if (p < NPAIR) {
            // closed-form triu decode (validated R6)
            int u = 119 - p;
            float sq = sqrtf((float)(8 * u + 1));
            int k = (int)((sq - 1.0f) * 0.5f);
            int i = 14 - k;
            int j = p - (i * (31 - i)) / 2 + i + 1;

            float2 xi = x2[(bg + bl) * NPART + i];
            float2 xj = x2[(bg + bl) * NPART + j];
            float dx = xi.x - xj.x, dy = xi.y - xj.y;
            float r = sqrtf(dx * dx + dy * dy + 1e-12f);

            float f0 = __logf(1.f + r);
            float f1 = r * __builtin_amdgcn_rcpf(1.f + r);
            float f2 = __expf(-r * r);
            float f3 = __expf(-0.5f * r);
            float f4 = __expf(-r);
            float f5 = f4 * f4;
            cusp = r * f4;                    // exact fp32

            v.u[0] = pk2(f0, f1);
            v.u[1] = pk2(f2, f3);
            v.u[2] = pk2(f4, f5);
            v.u[3] = 0u;
        }
        *(short8*)&s_f[(bl * 128 + p) * 8] = v.s;

        if (t < GB * NPART) {                 // 32 phi feature rows
            int bl2 = t >> 4, n = t & 15;
            float2 xv = x2[(bg + bl2) * NPART + n];
            float r2 = xv.x * xv.x + xv.y * xv.y;
            union { short8 s; unsigned u[4]; } w;
            w.u[0] = pk2(xv.x, xv.y);
            w.u[1] = pk2(r2, 0.f);
            w.u[2] = 0u; w.u[3] = 0u;
            *(short8*)&s_f[(PHI_ROW + t) * 8] = w.s;
        }
    }
    __syncthreads();

    const int colb = wv * 16 + m15;           // this lane's output column

    // ================= Phase 1: layer-1 MFMA + gelu + scatter ==================
    {
        short8 Bp1 = (short8)0, Bf1 = (short8)0;
        if (q == 0) {
            union { short8 s; unsigned u[4]; } bb;
            const float* w = psi_w0 + colb * 6;
            bb.u[0] = pk2(w[0], w[1]); bb.u[1] = pk2(w[2], w[3]);
            bb.u[2] = pk2(w[4], w[5]); bb.u[3] = 0u;
            Bp1 = bb.s;
            const float* wf = phi_w0 + colb * 3;
            bb.u[0] = pk2(wf[0], wf[1]); bb.u[1] = pk2(wf[2], 0.f);
            bb.u[2] = 0u; bb.u[3] = 0u;
            Bf1 = bb.s;
        }
        float b0p = psi_b0[colb];
        float b0f = phi_b0[colb];

#pragma unroll
        for (int bl = 0; bl < GB; ++bl)
#pragma unroll
            for (int Mt = 0; Mt < 8; ++Mt) {
                short8 a = (short8)0;
                if (q == 0) a = *(const short8*)&s_f[(bl * 128 + Mt * 16 + m15) * 8];
                floatx4 d = __builtin_amdgcn_mfma_f32_16x16x32_bf16(a, Bp1, (floatx4)0.f, 0, 0, 0);
#pragma unroll
                for (int rg = 0; rg < 4; ++rg) {
                    int row = bl * 128 + Mt * 16 + q * 4 + rg;
                    s_h[row * STRIDE + colb] = f2bfbits(gelu_sig(d[rg] + b0p));
                }
            }
#pragma unroll
        for (int bl = 0; bl < GB; ++bl) {
            short8 a = (short8)0;
            if (q == 0) a = *(const short8*)&s_f[(PHI_ROW + bl * 16 + m15) * 8];
            floatx4 d = __builtin_amdgcn_mfma_f32_16x16x32_bf16(a, Bf1, (floatx4)0.f, 0, 0, 0);
#pragma unroll
            for (int rg = 0; rg < 4; ++rg) {
                int row = PHI_ROW + bl * 16 + q * 4 + rg;
                s_h[row * STRIDE + colb] = f2bfbits(gelu_sig(d[rg] + b0f));
            }
        }
    }
    __syncthreads();

    // ================= Phase 2+3: layer-2 MFMA + gelu + colsums ================
    float csP[GB] = {0.f, 0.f};
    float csF[GB] = {0.f, 0.f};
    {
        short8 Bp2[2], Bf2[2];
#pragma unroll
        for (int Kc = 0; Kc < 2; ++Kc) {
            int k0 = Kc * 32 + q * 8;
            const float* wp = psi_w1 + colb * HID + k0;
            const float* wf = phi_w1 + colb * HID + k0;
            union { short8 s; unsigned u[4]; } bp, bf;
#pragma unroll
            for (int e2 = 0; e2 < 4; ++e2) {
                bp.u[e2] = pk2(wp[e2 * 2], wp[e2 * 2 + 1]);
                bf.u[e2] = pk2(wf[e2 * 2], wf[e2 * 2 + 1]);
            }
            Bp2[Kc] = bp.s; Bf2[Kc] = bf.s;
        }
        float b1p = psi_b1[colb];
        float b1f = phi_b1[colb];

#pragma unroll
        for (int bl = 0; bl < GB; ++bl)
#pragma unroll
            for (int Mt = 0; Mt < 8; ++Mt) {
                int ab = (bl * 128 + Mt * 16 + m15) * STRIDE + q * 8;
                short8 a0 = *(const short8*)&s_h[ab];
                short8 a1 = *(const short8*)&s_h[ab + 32];
                floatx4 acc = __builtin_amdgcn_mfma_f32_16x16x32_bf16(a0, Bp2[0], (floatx4)0.f, 0, 0, 0);
                acc = __builtin_amdgcn_mfma_f32_16x16x32_bf16(a1, Bp2[1], acc, 0, 0, 0);
                if (Mt == 7) {
                    if (q < 2) {    // rows 120..127 are pad -> exclude
#pragma unroll
                        for (int rg = 0; rg < 4; ++rg)
                            csP[bl] += gelu_sig(acc[rg] + b1p);
                    }
                } else {
#pragma unroll
                    for (int rg = 0; rg < 4; ++rg)
                        csP[bl] += gelu_sig(acc[rg] + b1p);
                }
            }
#pragma unroll
        for (int bl = 0; bl < GB; ++bl) {
            int ab = (PHI_ROW + bl * 16 + m15) * STRIDE + q * 8;
            short8 a0 = *(const short8*)&s_h[ab];
            short8 a1 = *(const short8*)&s_h[ab + 32];
            floatx4 acc = __builtin_amdgcn_mfma_f32_16x16x32_bf16(a0, Bf2[0], (floatx4)0.f, 0, 0, 0);
            acc = __builtin_amdgcn_mfma_f32_16x16x32_bf16(a1, Bf2[1], acc, 0, 0, 0);
#pragma unroll
            for (int rg = 0; rg < 4; ++rg)
                csF[bl] += gelu_sig(acc[rg] + b1f);
        }
    }
#pragma unroll
    for (int bl = 0; bl < GB; ++bl) {
        s_csP[bl][wv][q][m15] = csP[bl];
        s_csF[bl][wv][q][m15] = csF[bl];
    }
    {
        float cc = wred(cusp);
        if (lane == 0) s_cusp[wv] = cc;
    }
    __syncthreads();

    // ================= Phase 4: readout (wave 0 -> batch 0, wave 1 -> batch 1) ==
    if (t < 128) {
        const int blr = wv;
        const int c   = lane;      // column index 0..63
        float colP = s_csP[blr][c >> 4][0][c & 15] + s_csP[blr][c >> 4][1][c & 15]
                   + s_csP[blr][c >> 4][2][c & 15] + s_csP[blr][c >> 4][3][c & 15];
        float colF = s_csF[blr][c >> 4][0][c & 15] + s_csF[blr][c >> 4][1][c & 15]
                   + s_csF[blr][c >> 4][2][c & 15] + s_csF[blr][c >> 4][3][c & 15];

        float psiv[DL], phiv[DL];
#pragma unroll
        for (int d = 0; d < DL; ++d) {
            float sP = wred(colP * psi_w2[d * HID + c]);
            psiv[d] = __shfl(sP, 0) * (1.0f / NPAIR) + psi_b2[d];
            float sF = wred(colF * phi_w2[d * HID + c]);
            phiv[d] = __shfl(sF, 0) * (1.0f / NPART) + phi_b2[d];
        }

        int j = lane;
        float a = rho_b0[j];
        const float* wr = rho_w0 + j * (2 * DL);
#pragma unroll
        for (int d = 0; d < DL; ++d)
            a += phiv[d] * wr[d] + psiv[d] * wr[DL + d];
        float cuspb = s_cusp[2 * blr] + s_cusp[2 * blr + 1];
        float cv = gelu_sig(a) * rho_w1[j];
        cv = wred(cv);
        if (j == 0) out[bg + blr] = cv + rho_b1[0] + cuspb;
    }
}

extern "C" void kernel_launch(void* const* d_in, const int* in_sizes, int n_in,
                              void* d_out, int out_size, void* d_ws, size_t ws_size,
                              hipStream_t stream) {
    const float* x      = (const float*)d_in[0];
    const float* phi_w0 = (const float*)d_in[1];
    const float* phi_b0 = (const float*)d_in[2];
    const float* phi_w1 = (const float*)d_in[3];
    const float* phi_b1 = (const float*)d_in[4];
    const float* phi_w2 = (const float*)d_in[5];
    const float* phi_b2 = (const float*)d_in[6];
    const float* psi_w0 = (const float*)d_in[7];
    const float* psi_b0 = (const float*)d_in[8];
    const float* psi_w1 = (const float*)d_in[9];
    const float* psi_b1 = (const float*)d_in[10];
    const float* psi_w2 = (const float*)d_in[11];
    const float* psi_b2 = (const float*)d_in[12];
    const float* rho_w0 = (const float*)d_in[13];
    const float* rho_b0 = (const float*)d_in[14];
    const float* rho_w1 = (const float*)d_in[15];
    const float* rho_b1 = (const float*)d_in[16];

    jastrow_mfma4<<<B_TOT / GB, 256, 0, stream>>>(
        x,
        phi_w0, phi_b0, phi_w1, phi_b1, phi_w2, phi_b2,
        psi_w0, psi_b0, psi_w1, psi_b1, psi_w2, psi_b2,
        rho_w0, rho_b0, rho_w1, rho_b1,
        (float*)d_out);
}

// Round 8
// 188.466 us; speedup vs baseline: 1.3282x; 1.0880x over previous
//
#include <hip/hip_runtime.h>
#include <hip/hip_bf16.h>
#include <math.h>

#define B_TOT 16384
#define NPART 16
#define NPAIR 120     // 16*15/2
#define HID   64
#define DL    5
#define GB    2       // batch elements per block
#define PSI_BL 120    // psi h1 rows per batch element (no pad rows)
#define PHI_ROW 240   // 2*PSI_BL; phi rows [240,272)
#define NROW  272

typedef __attribute__((ext_vector_type(8))) short short8;
typedef __attribute__((ext_vector_type(4))) float floatx4;

// v * sigmoid(1.702 v)
__device__ __forceinline__ float gelu_sig(float v) {
    float e = __expf(-1.702f * v);
    return v * __builtin_amdgcn_rcpf(1.0f + e);
}

__device__ __forceinline__ unsigned pk2(float a, float b) {
    __hip_bfloat162 h = __float22bfloat162_rn(make_float2(a, b));
    union { __hip_bfloat162 h; unsigned u; } cv; cv.h = h;
    return cv.u;
}

__device__ __forceinline__ unsigned short f2bfbits(float f) {
    __hip_bfloat16 h = __float2bfloat16(f);
    union { __hip_bfloat16 h; unsigned short u; } cv; cv.h = h;
    return cv.u;
}

__device__ __forceinline__ float wred(float v) {
    v += __shfl_down(v, 32);
    v += __shfl_down(v, 16);
    v += __shfl_down(v, 8);
    v += __shfl_down(v, 4);
    v += __shfl_down(v, 2);
    v += __shfl_down(v, 1);
    return v;
}

// Block = 2 batch elements, 256 threads (4 waves). LDS ~39.2 KB -> 4 blocks/CU.
// h1 layout: stride 64, XOR-swizzled: (row,col) at s_h[row*64 + (col ^ ((row&7)*8))].
// No pad rows: out-of-range tile reads land in the neighboring region (garbage),
// provably masked from colsum; their stores are skipped.
// s_f (features, dead after phase 1) aliases s_cs (live after the phase-1 barrier).
__global__ __launch_bounds__(256) void jastrow_mfma5(
    const float* __restrict__ x,
    const float* __restrict__ phi_w0, const float* __restrict__ phi_b0,
    const float* __restrict__ phi_w1, const float* __restrict__ phi_b1,
    const float* __restrict__ phi_w2, const float* __restrict__ phi_b2,
    const float* __restrict__ psi_w0, const float* __restrict__ psi_b0,
    const float* __restrict__ psi_w1, const float* __restrict__ psi_b1,
    const float* __restrict__ psi_w2, const float* __restrict__ psi_b2,
    const float* __restrict__ rho_w0, const float* __restrict__ rho_b0,
    const float* __restrict__ rho_w1, const float* __restrict__ rho_b1,
    float* __restrict__ out)
{
    const int t    = threadIdx.x;
    const int lane = t & 63;
    const int wv   = t >> 6;
    const int q    = lane >> 4;
    const int m15  = lane & 15;
    const int bg   = blockIdx.x * GB;

    __shared__ __align__(16) unsigned short s_h[NROW * 64];  // 34816 B
    __shared__ __align__(16) unsigned char  s_mem[4352];     // s_f (phase<=1) | s_cs (phase>=3)
    __shared__ float s_cusp[4];

    unsigned short* s_f  = (unsigned short*)s_mem;           // [NROW][8] bf16 features
    float*          s_cs = (float*)s_mem;                    // [2][GB][4][4][16]

    const float2* x2 = (const float2*)x;
    float cusp = 0.f;

    // ================= Phase 0: features -> s_f ================================
    {
        const int bl = t >> 7;
        const int p  = t & 127;
        if (p < NPAIR) {
            int u = 119 - p;
            float sq = sqrtf((float)(8 * u + 1));
            int k = (int)((sq - 1.0f) * 0.5f);
            int i = 14 - k;
            int j = p - (i * (31 - i)) / 2 + i + 1;

            float2 xi = x2[(bg + bl) * NPART + i];
            float2 xj = x2[(bg + bl) * NPART + j];
            float dx = xi.x - xj.x, dy = xi.y - xj.y;
            float r = sqrtf(dx * dx + dy * dy + 1e-12f);

            float f0 = __logf(1.f + r);
            float f1 = r * __builtin_amdgcn_rcpf(1.f + r);
            float f2 = __expf(-r * r);
            float f3 = __expf(-0.5f * r);
            float f4 = __expf(-r);
            float f5 = f4 * f4;
            cusp = r * f4;                    // exact fp32

            union { short8 s; unsigned u4[4]; } v;
            v.u4[0] = pk2(f0, f1);
            v.u4[1] = pk2(f2, f3);
            v.u4[2] = pk2(f4, f5);
            v.u4[3] = 0u;
            *(short8*)&s_f[(bl * PSI_BL + p) * 8] = v.s;
        }
        if (t < GB * NPART) {                 // 32 phi feature rows
            int bl2 = t >> 4, n = t & 15;
            float2 xv = x2[(bg + bl2) * NPART + n];
            float r2 = xv.x * xv.x + xv.y * xv.y;
            union { short8 s; unsigned u4[4]; } w;
            w.u4[0] = pk2(xv.x, xv.y);
            w.u4[1] = pk2(r2, 0.f);
            w.u4[2] = 0u; w.u4[3] = 0u;
            *(short8*)&s_f[(PHI_ROW + t) * 8] = w.s;
        }
    }
    __syncthreads();

    const int colb = wv * 16 + m15;           // this lane's output column
    // swizzled column offsets for the 4 D-rows this lane stores (row&7 = (q*4+rg)&7)
    int swz[4];
#pragma unroll
    for (int rg = 0; rg < 4; ++rg) swz[rg] = colb ^ (((q * 4 + rg) & 7) << 3);

    // ================= Phase 1: layer-1 MFMA + gelu + swizzled scatter =========
    {
        short8 Bp1 = (short8)0, Bf1 = (short8)0;
        if (q == 0) {
            union { short8 s; unsigned u4[4]; } bb;
            const float* w = psi_w0 + colb * 6;
            bb.u4[0] = pk2(w[0], w[1]); bb.u4[1] = pk2(w[2], w[3]);
            bb.u4[2] = pk2(w[4], w[5]); bb.u4[3] = 0u;
            Bp1 = bb.s;
            const float* wf = phi_w0 + colb * 3;
            bb.u4[0] = pk2(wf[0], wf[1]); bb.u4[1] = pk2(wf[2], 0.f);
            bb.u4[2] = 0u; bb.u4[3] = 0u;
            Bf1 = bb.s;
        }
        float b0p = psi_b0[colb];
        float b0f = phi_b0[colb];
        floatx4 Cp = {b0p, b0p, b0p, b0p};
        floatx4 Cf = {b0f, b0f, b0f, b0f};

#pragma unroll
        for (int bl = 0; bl < GB; ++bl)
#pragma unroll
            for (int Mt = 0; Mt < 8; ++Mt) {
                int rowbase = bl * PSI_BL + Mt * 16;
                short8 a = (short8)0;
                if (q == 0) a = *(const short8*)&s_f[(rowbase + m15) * 8];
                floatx4 d = __builtin_amdgcn_mfma_f32_16x16x32_bf16(a, Bp1, Cp, 0, 0, 0);
                if (Mt < 7 || q < 2) {   // skip stores for pad D-rows 120..127
#pragma unroll
                    for (int rg = 0; rg < 4; ++rg)
                        s_h[(rowbase + q * 4 + rg) * 64 + swz[rg]] =
                            f2bfbits(gelu_sig(d[rg]));
                }
            }
#pragma unroll
        for (int bl = 0; bl < GB; ++bl) {
            int rowbase = PHI_ROW + bl * 16;
            short8 a = (short8)0;
            if (q == 0) a = *(const short8*)&s_f[(rowbase + m15) * 8];
            floatx4 d = __builtin_amdgcn_mfma_f32_16x16x32_bf16(a, Bf1, Cf, 0, 0, 0);
#pragma unroll
            for (int rg = 0; rg < 4; ++rg)
                s_h[(rowbase + q * 4 + rg) * 64 + swz[rg]] =
                    f2bfbits(gelu_sig(d[rg]));
        }
    }
    __syncthreads();

    // ================= Phase 2+3: layer-2 MFMA + gelu + colsums ================
    float csP[GB] = {0.f, 0.f};
    float csF[GB] = {0.f, 0.f};
    {
        short8 Bp2[2], Bf2[2];
#pragma unroll
        for (int Kc = 0; Kc < 2; ++Kc) {
            int k0 = Kc * 32 + q * 8;
            const float* wp = psi_w1 + colb * HID + k0;
            const float* wf = phi_w1 + colb * HID + k0;
            union { short8 s; unsigned u4[4]; } bp, bf;
#pragma unroll
            for (int e2 = 0; e2 < 4; ++e2) {
                bp.u4[e2] = pk2(wp[e2 * 2], wp[e2 * 2 + 1]);
                bf.u4[e2] = pk2(wf[e2 * 2], wf[e2 * 2 + 1]);
            }
            Bp2[Kc] = bp.s; Bf2[Kc] = bf.s;
        }
        float b1p = psi_b1[colb];
        float b1f = phi_b1[colb];
        floatx4 Cp = {b1p, b1p, b1p, b1p};
        floatx4 Cf = {b1f, b1f, b1f, b1f};

        // swizzled read offsets: A-row = ...+m15 -> row&7 = m15&7 (all bases %8==0)
        const int h  = m15 & 7;
        const int g0 = (q ^ h) << 3;          // K-chunk 0 (cols q*8..+7)
        const int g1 = g0 ^ 32;               // K-chunk 1 (cols 32+q*8..+7)

#pragma unroll
        for (int bl = 0; bl < GB; ++bl)
#pragma unroll
            for (int Mt = 0; Mt < 8; ++Mt) {
                int rb = (bl * PSI_BL + Mt * 16 + m15) * 64;
                short8 a0 = *(const short8*)&s_h[rb + g0];
                short8 a1 = *(const short8*)&s_h[rb + g1];
                floatx4 acc = __builtin_amdgcn_mfma_f32_16x16x32_bf16(a0, Bp2[0], Cp, 0, 0, 0);
                acc = __builtin_amdgcn_mfma_f32_16x16x32_bf16(a1, Bp2[1], acc, 0, 0, 0);
                if (Mt == 7) {
                    if (q < 2) {              // D-rows 120..127 are garbage -> exclude
#pragma unroll
                        for (int rg = 0; rg < 4; ++rg)
                            csP[bl] += gelu_sig(acc[rg]);
                    }
                } else {
#pragma unroll
                    for (int rg = 0; rg < 4; ++rg)
                        csP[bl] += gelu_sig(acc[rg]);
                }
            }
#pragma unroll
        for (int bl = 0; bl < GB; ++bl) {
            int rb = (PHI_ROW + bl * 16 + m15) * 64;
            short8 a0 = *(const short8*)&s_h[rb + g0];
            short8 a1 = *(const short8*)&s_h[rb + g1];
            floatx4 acc = __builtin_amdgcn_mfma_f32_16x16x32_bf16(a0, Bf2[0], Cf, 0, 0, 0);
            acc = __builtin_amdgcn_mfma_f32_16x16x32_bf16(a1, Bf2[1], acc, 0, 0, 0);
#pragma unroll
            for (int rg = 0; rg < 4; ++rg)
                csF[bl] += gelu_sig(acc[rg]);
        }
    }
    // store colsum partials (s_f is dead; s_cs aliases it — separated by barriers)
#pragma unroll
    for (int bl = 0; bl < GB; ++bl) {
        s_cs[(((0 * GB + bl) * 4 + wv) * 4 + q) * 16 + m15] = csP[bl];
        s_cs[(((1 * GB + bl) * 4 + wv) * 4 + q) * 16 + m15] = csF[bl];
    }
    {
        float cc = wred(cusp);
        if (lane == 0) s_cusp[wv] = cc;
    }
    __syncthreads();

    // ================= Phase 4: readout (wave 0 -> batch 0, wave 1 -> batch 1) ==
    if (t < 128) {
        const int blr = wv;
        const int c   = lane;
        const int cw  = c >> 4, cm = c & 15;
        float colP = 0.f, colF = 0.f;
#pragma unroll
        for (int qq = 0; qq < 4; ++qq) {
            colP += s_cs[(((0 * GB + blr) * 4 + cw) * 4 + qq) * 16 + cm];
            colF += s_cs[(((1 * GB + blr) * 4 + cw) * 4 + qq) * 16 + cm];
        }

        float psiv[DL], phiv[DL];
#pragma unroll
        for (int d = 0; d < DL; ++d) {
            float sP = wred(colP * psi_w2[d * HID + c]);
            psiv[d] = __shfl(sP, 0) * (1.0f / NPAIR) + psi_b2[d];
            float sF = wred(colF * phi_w2[d * HID + c]);
            phiv[d] = __shfl(sF, 0) * (1.0f / NPART) + phi_b2[d];
        }

        int j = lane;
        float a = rho_b0[j];
        const float* wr = rho_w0 + j * (2 * DL);
#pragma unroll
        for (int d = 0; d < DL; ++d)
            a += phiv[d] * wr[d] + psiv[d] * wr[DL + d];
        float cuspb = s_cusp[2 * blr] + s_cusp[2 * blr + 1];
        float cv = gelu_sig(a) * rho_w1[j];
        cv = wred(cv);
        if (j == 0) out[bg + blr] = cv + rho_b1[0] + cuspb;
    }
}

extern "C" void kernel_launch(void* const* d_in, const int* in_sizes, int n_in,
                              void* d_out, int out_size, void* d_ws, size_t ws_size,
                              hipStream_t stream) {
    const float* x      = (const float*)d_in[0];
    const float* phi_w0 = (const float*)d_in[1];
    const float* phi_b0 = (const float*)d_in[2];
    const float* phi_w1 = (const float*)d_in[3];
    const float* phi_b1 = (const float*)d_in[4];
    const float* phi_w2 = (const float*)d_in[5];
    const float* phi_b2 = (const float*)d_in[6];
    const float* psi_w0 = (const float*)d_in[7];
    const float* psi_b0 = (const float*)d_in[8];
    const float* psi_w1 = (const float*)d_in[9];
    const float* psi_b1 = (const float*)d_in[10];
    const float* psi_w2 = (const float*)d_in[11];
    const float* psi_b2 = (const float*)d_in[12];
    const float* rho_w0 = (const float*)d_in[13];
    const float* rho_b0 = (const float*)d_in[14];
    const float* rho_w1 = (const float*)d_in[15];
    const float* rho_b1 = (const float*)d_in[16];

    jastrow_mfma5<<<B_TOT / GB, 256, 0, stream>>>(
        x,
        phi_w0, phi_b0, phi_w1, phi_b1, phi_w2, phi_b2,
        psi_w0, psi_b0, psi_w1, psi_b1, psi_w2, psi_b2,
        rho_w0, rho_b0, rho_w1, rho_b1,
        (float*)d_out);
}

// Round 9
// 182.529 us; speedup vs baseline: 1.3714x; 1.0325x over previous
//
#include <hip/hip_runtime.h>
#include <hip/hip_bf16.h>
#include <math.h>

#define B_TOT 16384
#define NPART 16
#define NPAIR 120     // 16*15/2
#define HID   64
#define DL    5
#define GB    2       // batch elements per block (serialized through s_h)
#define PSI_ROWS 120  // psi h1 rows resident per iteration
#define PHI_HROW 120  // phi h1 rows live at s_h rows [120,136)
#define NROW_IT  136
#define SF_PHI   240  // phi feature rows in s_f at [240,272)

typedef __attribute__((ext_vector_type(8))) short short8;
typedef __attribute__((ext_vector_type(4))) float floatx4;

// v * sigmoid(1.702 v)
__device__ __forceinline__ float gelu_sig(float v) {
    float e = __expf(-1.702f * v);
    return v * __builtin_amdgcn_rcpf(1.0f + e);
}

__device__ __forceinline__ unsigned pk2(float a, float b) {
    __hip_bfloat162 h = __float22bfloat162_rn(make_float2(a, b));
    union { __hip_bfloat162 h; unsigned u; } cv; cv.h = h;
    return cv.u;
}

__device__ __forceinline__ unsigned short f2bfbits(float f) {
    __hip_bfloat16 h = __float2bfloat16(f);
    union { __hip_bfloat16 h; unsigned short u; } cv; cv.h = h;
    return cv.u;
}

__device__ __forceinline__ float wred(float v) {
    v += __shfl_down(v, 32);
    v += __shfl_down(v, 16);
    v += __shfl_down(v, 8);
    v += __shfl_down(v, 4);
    v += __shfl_down(v, 2);
    v += __shfl_down(v, 1);
    return v;
}

// Block = 2 batch elements, 256 threads (4 waves).
// LDS ~21.8 KB -> 7 blocks/CU (was 39.4 KB / 4 blocks): the two batch
// elements are serialized through ONE half-size s_h region (2 extra barriers).
// h1 layout: stride 64, XOR swizzle (row,col) -> s_h[row*64 + (col ^ ((row&7)<<3))].
// Layer-1 and layer-2 via MFMA 16x16x32 bf16; layer-3 folded into column sums
// (row-mean commutes with matmul). Cusp exact fp32. s_f aliases s_cs (disjoint
// lifetimes, separated by barriers).
__global__ __launch_bounds__(256) void jastrow_mfma6(
    const float* __restrict__ x,
    const float* __restrict__ phi_w0, const float* __restrict__ phi_b0,
    const float* __restrict__ phi_w1, const float* __restrict__ phi_b1,
    const float* __restrict__ phi_w2, const float* __restrict__ phi_b2,
    const float* __restrict__ psi_w0, const float* __restrict__ psi_b0,
    const float* __restrict__ psi_w1, const float* __restrict__ psi_b1,
    const float* __restrict__ psi_w2, const float* __restrict__ psi_b2,
    const float* __restrict__ rho_w0, const float* __restrict__ rho_b0,
    const float* __restrict__ rho_w1, const float* __restrict__ rho_b1,
    float* __restrict__ out)
{
    const int t    = threadIdx.x;
    const int lane = t & 63;
    const int wv   = t >> 6;
    const int q    = lane >> 4;
    const int m15  = lane & 15;
    const int bg   = blockIdx.x * GB;

    __shared__ __align__(16) unsigned short s_h[NROW_IT * 64];   // 17408 B
    __shared__ __align__(16) unsigned char  s_mem[4352];         // s_f | s_cs
    __shared__ float s_cusp[4];

    unsigned short* s_f  = (unsigned short*)s_mem;  // [272][8] bf16 features
    float*          s_cs = (float*)s_mem;           // [2][GB][4][4][16] colsum partials

    const float2* x2 = (const float2*)x;
    float cusp = 0.f;

    // ================= Phase 0: features (both batches) -> s_f =================
    {
        const int bl = t >> 7;
        const int p  = t & 127;
        if (p < NPAIR) {
            int u = 119 - p;
            float sq = sqrtf((float)(8 * u + 1));
            int k = (int)((sq - 1.0f) * 0.5f);
            int i = 14 - k;
            int j = p - (i * (31 - i)) / 2 + i + 1;

            float2 xi = x2[(bg + bl) * NPART + i];
            float2 xj = x2[(bg + bl) * NPART + j];
            float dx = xi.x - xj.x, dy = xi.y - xj.y;
            float r = sqrtf(dx * dx + dy * dy + 1e-12f);

            float f0 = __logf(1.f + r);
            float f1 = r * __builtin_amdgcn_rcpf(1.f + r);
            float f2 = __expf(-r * r);
            float f3 = __expf(-0.5f * r);
            float f4 = __expf(-r);
            float f5 = f4 * f4;
            cusp = r * f4;                    // exact fp32

            union { short8 s; unsigned u4[4]; } v;
            v.u4[0] = pk2(f0, f1);
            v.u4[1] = pk2(f2, f3);
            v.u4[2] = pk2(f4, f5);
            v.u4[3] = 0u;
            *(short8*)&s_f[(bl * PSI_ROWS + p) * 8] = v.s;
        }
        if (t < GB * NPART) {                 // 32 phi feature rows
            int bl2 = t >> 4, n = t & 15;
            float2 xv = x2[(bg + bl2) * NPART + n];
            float r2 = xv.x * xv.x + xv.y * xv.y;
            union { short8 s; unsigned u4[4]; } w;
            w.u4[0] = pk2(xv.x, xv.y);
            w.u4[1] = pk2(r2, 0.f);
            w.u4[2] = 0u; w.u4[3] = 0u;
            *(short8*)&s_f[(SF_PHI + t) * 8] = w.s;
        }
    }

    const int colb = wv * 16 + m15;           // this lane's output column
    int swz[4];
#pragma unroll
    for (int rg = 0; rg < 4; ++rg) swz[rg] = colb ^ (((q * 4 + rg) & 7) << 3);

    // --------- hoisted B-fragments + biases (live across both iterations) ------
    short8 Bp1 = (short8)0, Bf1 = (short8)0;
    if (q == 0) {
        union { short8 s; unsigned u4[4]; } bb;
        const float* w = psi_w0 + colb * 6;
        bb.u4[0] = pk2(w[0], w[1]); bb.u4[1] = pk2(w[2], w[3]);
        bb.u4[2] = pk2(w[4], w[5]); bb.u4[3] = 0u;
        Bp1 = bb.s;
        const float* wf = phi_w0 + colb * 3;
        bb.u4[0] = pk2(wf[0], wf[1]); bb.u4[1] = pk2(wf[2], 0.f);
        bb.u4[2] = 0u; bb.u4[3] = 0u;
        Bf1 = bb.s;
    }
    float b0p = psi_b0[colb], b0f = phi_b0[colb];
    floatx4 C0p = {b0p, b0p, b0p, b0p};
    floatx4 C0f = {b0f, b0f, b0f, b0f};

    short8 Bp2[2], Bf2[2];
#pragma unroll
    for (int Kc = 0; Kc < 2; ++Kc) {
        int k0 = Kc * 32 + q * 8;
        const float* wp = psi_w1 + colb * HID + k0;
        const float* wf = phi_w1 + colb * HID + k0;
        union { short8 s; unsigned u4[4]; } bp, bf;
#pragma unroll
        for (int e2 = 0; e2 < 4; ++e2) {
            bp.u4[e2] = pk2(wp[e2 * 2], wp[e2 * 2 + 1]);
            bf.u4[e2] = pk2(wf[e2 * 2], wf[e2 * 2 + 1]);
        }
        Bp2[Kc] = bp.s; Bf2[Kc] = bf.s;
    }
    float b1p = psi_b1[colb], b1f = phi_b1[colb];
    floatx4 C1p = {b1p, b1p, b1p, b1p};
    floatx4 C1f = {b1f, b1f, b1f, b1f};

    // swizzled A-read offsets for layer-2 (row&7 = m15&7; all row bases %8==0)
    const int g0 = ((q ^ (m15 & 7)) << 3);
    const int g1 = g0 ^ 32;

    float csP[GB] = {0.f, 0.f};
    float csF[GB] = {0.f, 0.f};

    __syncthreads();   // s_f ready

    // ================= serialized per-batch iterations =========================
#pragma unroll
    for (int bl = 0; bl < GB; ++bl) {
        // ---- Phase 1: layer-1 MFMA + gelu + swizzled scatter into s_h --------
#pragma unroll
        for (int Mt = 0; Mt < 8; ++Mt) {
            short8 a = (short8)0;
            if (q == 0) a = *(const short8*)&s_f[(bl * PSI_ROWS + Mt * 16 + m15) * 8];
            floatx4 d = __builtin_amdgcn_mfma_f32_16x16x32_bf16(a, Bp1, C0p, 0, 0, 0);
            if (Mt < 7 || q < 2) {   // D-rows 120..127 don't exist -> skip
#pragma unroll
                for (int rg = 0; rg < 4; ++rg)
                    s_h[(Mt * 16 + q * 4 + rg) * 64 + swz[rg]] =
                        f2bfbits(gelu_sig(d[rg]));
            }
        }
        {
            short8 a = (short8)0;
            if (q == 0) a = *(const short8*)&s_f[(SF_PHI + bl * 16 + m15) * 8];
            floatx4 d = __builtin_amdgcn_mfma_f32_16x16x32_bf16(a, Bf1, C0f, 0, 0, 0);
#pragma unroll
            for (int rg = 0; rg < 4; ++rg)
                s_h[(PHI_HROW + q * 4 + rg) * 64 + swz[rg]] =
                    f2bfbits(gelu_sig(d[rg]));
        }
        __syncthreads();   // h1 ready

        // ---- Phase 2+3: layer-2 MFMA + gelu + colsum accumulate ---------------
#pragma unroll
        for (int Mt = 0; Mt < 8; ++Mt) {
            int rb = (Mt * 16 + m15) * 64;
            short8 a0 = *(const short8*)&s_h[rb + g0];
            short8 a1 = *(const short8*)&s_h[rb + g1];
            floatx4 acc = __builtin_amdgcn_mfma_f32_16x16x32_bf16(a0, Bp2[0], C1p, 0, 0, 0);
            acc = __builtin_amdgcn_mfma_f32_16x16x32_bf16(a1, Bp2[1], acc, 0, 0, 0);
            if (Mt == 7) {
                if (q < 2) {       // D-rows 120..127 are garbage (phi region) -> exclude
#pragma unroll
                    for (int rg = 0; rg < 4; ++rg)
                        csP[bl] += gelu_sig(acc[rg]);
                }
            } else {
#pragma unroll
                for (int rg = 0; rg < 4; ++rg)
                    csP[bl] += gelu_sig(acc[rg]);
            }
        }
        {
            int rb = (PHI_HROW + m15) * 64;
            short8 a0 = *(const short8*)&s_h[rb + g0];
            short8 a1 = *(const short8*)&s_h[rb + g1];
            floatx4 acc = __builtin_amdgcn_mfma_f32_16x16x32_bf16(a0, Bf2[0], C1f, 0, 0, 0);
            acc = __builtin_amdgcn_mfma_f32_16x16x32_bf16(a1, Bf2[1], acc, 0, 0, 0);
#pragma unroll
            for (int rg = 0; rg < 4; ++rg)
                csF[bl] += gelu_sig(acc[rg]);
        }
        __syncthreads();   // s_h consumed; safe to overwrite next iteration
    }

    // ---- store colsum partials (s_f dead -> s_cs aliases it) ------------------
#pragma unroll
    for (int bl = 0; bl < GB; ++bl) {
        s_cs[(((0 * GB + bl) * 4 + wv) * 4 + q) * 16 + m15] = csP[bl];
        s_cs[(((1 * GB + bl) * 4 + wv) * 4 + q) * 16 + m15] = csF[bl];
    }
    {
        float cc = wred(cusp);
        if (lane == 0) s_cusp[wv] = cc;
    }
    __syncthreads();

    // ================= Phase 4: readout (wave 0 -> b0, wave 1 -> b1) ===========
    if (t < 128) {
        const int blr = wv;
        const int c   = lane;
        const int cw  = c >> 4, cm = c & 15;
        float colP = 0.f, colF = 0.f;
#pragma unroll
        for (int qq = 0; qq < 4; ++qq) {
            colP += s_cs[(((0 * GB + blr) * 4 + cw) * 4 + qq) * 16 + cm];
            colF += s_cs[(((1 * GB + blr) * 4 + cw) * 4 + qq) * 16 + cm];
        }

        float psiv[DL], phiv[DL];
#pragma unroll
        for (int d = 0; d < DL; ++d) {
            float sP = wred(colP * psi_w2[d * HID + c]);
            psiv[d] = __shfl(sP, 0) * (1.0f / NPAIR) + psi_b2[d];
            float sF = wred(colF * phi_w2[d * HID + c]);
            phiv[d] = __shfl(sF, 0) * (1.0f / NPART) + phi_b2[d];
        }

        int j = lane;
        float a = rho_b0[j];
        const float* wr = rho_w0 + j * (2 * DL);
#pragma unroll
        for (int d = 0; d < DL; ++d)
            a += phiv[d] * wr[d] + psiv[d] * wr[DL + d];
        float cuspb = s_cusp[2 * blr] + s_cusp[2 * blr + 1];
        float cv = gelu_sig(a) * rho_w1[j];
        cv = wred(cv);
        if (j == 0) out[bg + blr] = cv + rho_b1[0] + cuspb;
    }
}

extern "C" void kernel_launch(void* const* d_in, const int* in_sizes, int n_in,
                              void* d_out, int out_size, void* d_ws, size_t ws_size,
                              hipStream_t stream) {
    const float* x      = (const float*)d_in[0];
    const float* phi_w0 = (const float*)d_in[1];
    const float* phi_b0 = (const float*)d_in[2];
    const float* phi_w1 = (const float*)d_in[3];
    const float* phi_b1 = (const float*)d_in[4];
    const float* phi_w2 = (const float*)d_in[5];
    const float* phi_b2 = (const float*)d_in[6];
    const float* psi_w0 = (const float*)d_in[7];
    const float* psi_b0 = (const float*)d_in[8];
    const float* psi_w1 = (const float*)d_in[9];
    const float* psi_b1 = (const float*)d_in[10];
    const float* psi_w2 = (const float*)d_in[11];
    const float* psi_b2 = (const float*)d_in[12];
    const float* rho_w0 = (const float*)d_in[13];
    const float* rho_b0 = (const float*)d_in[14];
    const float* rho_w1 = (const float*)d_in[15];
    const float* rho_b1 = (const float*)d_in[16];

    jastrow_mfma6<<<B_TOT / GB, 256, 0, stream>>>(
        x,
        phi_w0, phi_b0, phi_w1, phi_b1, phi_w2, phi_b2,
        psi_w0, psi_b0, psi_w1, psi_b1, psi_w2, psi_b2,
        rho_w0, rho_b0, rho_w1, rho_b1,
        (float*)d_out);
}

// Round 10
// 179.274 us; speedup vs baseline: 1.3963x; 1.0182x over previous
//
#include <hip/hip_runtime.h>
#include <hip/hip_bf16.h>
#include <math.h>

#define B_TOT 16384
#define NPART 16
#define NPAIR 120     // 16*15/2
#define HID   64
#define DL    5
#define GB    2       // batch elements per block (serialized through s_h)
#define PSI_ROWS 120  // psi h1 rows resident per iteration
#define PHI_HROW 120  // phi h1 rows live at s_h rows [120,136)
#define NROW_IT  136
#define SF_PHI   240  // phi feature rows in s_f at [240,272)

typedef __attribute__((ext_vector_type(8))) short short8;
typedef __attribute__((ext_vector_type(4))) float floatx4;

// Minimal-instruction sigmoid-GELU: v * sigmoid(1.702 v)
//   = v * rcp(1 + 2^(-1.702*log2(e)*v)) : v_mul, v_exp, v_add, v_rcp, v_mul.
// __builtin_amdgcn_exp2f is raw v_exp_f32 (no ocml range reduction).
__device__ __forceinline__ float gelu_sig(float v) {
    float e = __builtin_amdgcn_exp2f(-2.45556851f * v);
    return v * __builtin_amdgcn_rcpf(1.0f + e);
}

__device__ __forceinline__ unsigned pk2(float a, float b) {
    __hip_bfloat162 h = __float22bfloat162_rn(make_float2(a, b));
    union { __hip_bfloat162 h; unsigned u; } cv; cv.h = h;
    return cv.u;
}

__device__ __forceinline__ unsigned short f2bfbits(float f) {
    __hip_bfloat16 h = __float2bfloat16(f);
    union { __hip_bfloat16 h; unsigned short u; } cv; cv.h = h;
    return cv.u;
}

__device__ __forceinline__ float wred(float v) {
    v += __shfl_down(v, 32);
    v += __shfl_down(v, 16);
    v += __shfl_down(v, 8);
    v += __shfl_down(v, 4);
    v += __shfl_down(v, 2);
    v += __shfl_down(v, 1);
    return v;
}

// Block = 2 batch elements, 256 threads (4 waves). LDS ~21.8 KB.
// h1 layout: stride 64, XOR swizzle (row,col) -> s_h[row*64 + (col ^ ((row&7)<<3))].
// Layer-1 and layer-2 via MFMA 16x16x32 bf16; layer-3 folded into column sums
// (row-mean commutes with matmul). Cusp exact fp32. All transcendentals via
// raw v_exp_f32/v_log_f32 builtins (R10: kill ocml range-reduction overhead).
__global__ __launch_bounds__(256) void jastrow_mfma7(
    const float* __restrict__ x,
    const float* __restrict__ phi_w0, const float* __restrict__ phi_b0,
    const float* __restrict__ phi_w1, const float* __restrict__ phi_b1,
    const float* __restrict__ phi_w2, const float* __restrict__ phi_b2,
    const float* __restrict__ psi_w0, const float* __restrict__ psi_b0,
    const float* __restrict__ psi_w1, const float* __restrict__ psi_b1,
    const float* __restrict__ psi_w2, const float* __restrict__ psi_b2,
    const float* __restrict__ rho_w0, const float* __restrict__ rho_b0,
    const float* __restrict__ rho_w1, const float* __restrict__ rho_b1,
    float* __restrict__ out)
{
    const int t    = threadIdx.x;
    const int lane = t & 63;
    const int wv   = t >> 6;
    const int q    = lane >> 4;
    const int m15  = lane & 15;
    const int bg   = blockIdx.x * GB;

    __shared__ __align__(16) unsigned short s_h[NROW_IT * 64];   // 17408 B
    __shared__ __align__(16) unsigned char  s_mem[4352];         // s_f | s_cs
    __shared__ float s_cusp[4];

    unsigned short* s_f  = (unsigned short*)s_mem;  // [272][8] bf16 features
    float*          s_cs = (float*)s_mem;           // [2][GB][4][4][16] colsum partials

    const float2* x2 = (const float2*)x;
    float cusp = 0.f;

    // ================= Phase 0: features (both batches) -> s_f =================
    {
        const int bl = t >> 7;
        const int p  = t & 127;
        if (p < NPAIR) {
            int u = 119 - p;
            float sq = sqrtf((float)(8 * u + 1));
            int k = (int)((sq - 1.0f) * 0.5f);
            int i = 14 - k;
            int j = p - (i * (31 - i)) / 2 + i + 1;

            float2 xi = x2[(bg + bl) * NPART + i];
            float2 xj = x2[(bg + bl) * NPART + j];
            float dx = xi.x - xj.x, dy = xi.y - xj.y;
            float r = sqrtf(dx * dx + dy * dy + 1e-12f);

            // f0=log1p(r), f1=r/(1+r), f2=exp(-r^2), f3=exp(-r/2), f4=exp(-r), f5=exp(-2r)
            float f0 = 0.69314718056f * __builtin_amdgcn_logf(1.f + r);   // v_log = log2
            float f1 = r * __builtin_amdgcn_rcpf(1.f + r);
            float f3 = __builtin_amdgcn_exp2f(-0.72134752044f * r);       // exp(-r/2)
            float f4 = f3 * f3;                                           // exp(-r)
            float f5 = f4 * f4;                                           // exp(-2r)
            float f2 = __builtin_amdgcn_exp2f(-1.44269504089f * r * r);   // exp(-r^2)
            cusp = r * f4;                    // exact fp32 (f4 = ulp-level exp(-r))

            union { short8 s; unsigned u4[4]; } v;
            v.u4[0] = pk2(f0, f1);
            v.u4[1] = pk2(f2, f3);
            v.u4[2] = pk2(f4, f5);
            v.u4[3] = 0u;
            *(short8*)&s_f[(bl * PSI_ROWS + p) * 8] = v.s;
        }
        if (t < GB * NPART) {                 // 32 phi feature rows
            int bl2 = t >> 4, n = t & 15;
            float2 xv = x2[(bg + bl2) * NPART + n];
            float r2 = xv.x * xv.x + xv.y * xv.y;
            union { short8 s; unsigned u4[4]; } w;
            w.u4[0] = pk2(xv.x, xv.y);
            w.u4[1] = pk2(r2, 0.f);
            w.u4[2] = 0u; w.u4[3] = 0u;
            *(short8*)&s_f[(SF_PHI + t) * 8] = w.s;
        }
    }

    const int colb = wv * 16 + m15;           // this lane's output column
    int swz[4];
#pragma unroll
    for (int rg = 0; rg < 4; ++rg) swz[rg] = colb ^ (((q * 4 + rg) & 7) << 3);

    // --------- hoisted B-fragments + biases (live across both iterations) ------
    short8 Bp1 = (short8)0, Bf1 = (short8)0;
    if (q == 0) {
        union { short8 s; unsigned u4[4]; } bb;
        const float* w = psi_w0 + colb * 6;
        bb.u4[0] = pk2(w[0], w[1]); bb.u4[1] = pk2(w[2], w[3]);
        bb.u4[2] = pk2(w[4], w[5]); bb.u4[3] = 0u;
        Bp1 = bb.s;
        const float* wf = phi_w0 + colb * 3;
        bb.u4[0] = pk2(wf[0], wf[1]); bb.u4[1] = pk2(wf[2], 0.f);
        bb.u4[2] = 0u; bb.u4[3] = 0u;
        Bf1 = bb.s;
    }
    float b0p = psi_b0[colb], b0f = phi_b0[colb];
    floatx4 C0p = {b0p, b0p, b0p, b0p};
    floatx4 C0f = {b0f, b0f, b0f, b0f};

    short8 Bp2[2], Bf2[2];
#pragma unroll
    for (int Kc = 0; Kc < 2; ++Kc) {
        int k0 = Kc * 32 + q * 8;
        const float* wp = psi_w1 + colb * HID + k0;
        const float* wf = phi_w1 + colb * HID + k0;
        union { short8 s; unsigned u4[4]; } bp, bf;
#pragma unroll
        for (int e2 = 0; e2 < 4; ++e2) {
            bp.u4[e2] = pk2(wp[e2 * 2], wp[e2 * 2 + 1]);
            bf.u4[e2] = pk2(wf[e2 * 2], wf[e2 * 2 + 1]);
        }
        Bp2[Kc] = bp.s; Bf2[Kc] = bf.s;
    }
    float b1p = psi_b1[colb], b1f = phi_b1[colb];
    floatx4 C1p = {b1p, b1p, b1p, b1p};
    floatx4 C1f = {b1f, b1f, b1f, b1f};

    // swizzled A-read offsets for layer-2 (row&7 = m15&7; all row bases %8==0)
    const int g0 = ((q ^ (m15 & 7)) << 3);
    const int g1 = g0 ^ 32;

    float csP[GB] = {0.f, 0.f};
    float csF[GB] = {0.f, 0.f};

    __syncthreads();   // s_f ready

    // ================= serialized per-batch iterations =========================
#pragma unroll
    for (int bl = 0; bl < GB; ++bl) {
        // ---- Phase 1: layer-1 MFMA + gelu + swizzled scatter into s_h --------
#pragma unroll
        for (int Mt = 0; Mt < 8; ++Mt) {
            short8 a = (short8)0;
            if (q == 0) a = *(const short8*)&s_f[(bl * PSI_ROWS + Mt * 16 + m15) * 8];
            floatx4 d = __builtin_amdgcn_mfma_f32_16x16x32_bf16(a, Bp1, C0p, 0, 0, 0);
            if (Mt < 7 || q < 2) {   // D-rows 120..127 don't exist -> skip
#pragma unroll
                for (int rg = 0; rg < 4; ++rg)
                    s_h[(Mt * 16 + q * 4 + rg) * 64 + swz[rg]] =
                        f2bfbits(gelu_sig(d[rg]));
            }
        }
        {
            short8 a = (short8)0;
            if (q == 0) a = *(const short8*)&s_f[(SF_PHI + bl * 16 + m15) * 8];
            floatx4 d = __builtin_amdgcn_mfma_f32_16x16x32_bf16(a, Bf1, C0f, 0, 0, 0);
#pragma unroll
            for (int rg = 0; rg < 4; ++rg)
                s_h[(PHI_HROW + q * 4 + rg) * 64 + swz[rg]] =
                    f2bfbits(gelu_sig(d[rg]));
        }
        __syncthreads();   // h1 ready

        // ---- Phase 2+3: layer-2 MFMA + gelu + colsum accumulate ---------------
#pragma unroll
        for (int Mt = 0; Mt < 8; ++Mt) {
            int rb = (Mt * 16 + m15) * 64;
            short8 a0 = *(const short8*)&s_h[rb + g0];
            short8 a1 = *(const short8*)&s_h[rb + g1];
            floatx4 acc = __builtin_amdgcn_mfma_f32_16x16x32_bf16(a0, Bp2[0], C1p, 0, 0, 0);
            acc = __builtin_amdgcn_mfma_f32_16x16x32_bf16(a1, Bp2[1], acc, 0, 0, 0);
            if (Mt == 7) {
                if (q < 2) {       // D-rows 120..127 are garbage (phi region) -> exclude
#pragma unroll
                    for (int rg = 0; rg < 4; ++rg)
                        csP[bl] += gelu_sig(acc[rg]);
                }
            } else {
#pragma unroll
                for (int rg = 0; rg < 4; ++rg)
                    csP[bl] += gelu_sig(acc[rg]);
            }
        }
        {
            int rb = (PHI_HROW + m15) * 64;
            short8 a0 = *(const short8*)&s_h[rb + g0];
            short8 a1 = *(const short8*)&s_h[rb + g1];
            floatx4 acc = __builtin_amdgcn_mfma_f32_16x16x32_bf16(a0, Bf2[0], C1f, 0, 0, 0);
            acc = __builtin_amdgcn_mfma_f32_16x16x32_bf16(a1, Bf2[1], acc, 0, 0, 0);
#pragma unroll
            for (int rg = 0; rg < 4; ++rg)
                csF[bl] += gelu_sig(acc[rg]);
        }
        __syncthreads();   // s_h consumed; safe to overwrite next iteration
    }

    // ---- store colsum partials (s_f dead -> s_cs aliases it) ------------------
#pragma unroll
    for (int bl = 0; bl < GB; ++bl) {
        s_cs[(((0 * GB + bl) * 4 + wv) * 4 + q) * 16 + m15] = csP[bl];
        s_cs[(((1 * GB + bl) * 4 + wv) * 4 + q) * 16 + m15] = csF[bl];
    }
    {
        float cc = wred(cusp);
        if (lane == 0) s_cusp[wv] = cc;
    }
    __syncthreads();

    // ================= Phase 4: readout (wave 0 -> b0, wave 1 -> b1) ===========
    if (t < 128) {
        const int blr = wv;
        const int c   = lane;
        const int cw  = c >> 4, cm = c & 15;
        float colP = 0.f, colF = 0.f;
#pragma unroll
        for (int qq = 0; qq < 4; ++qq) {
            colP += s_cs[(((0 * GB + blr) * 4 + cw) * 4 + qq) * 16 + cm];
            colF += s_cs[(((1 * GB + blr) * 4 + cw) * 4 + qq) * 16 + cm];
        }

        float psiv[DL], phiv[DL];
#pragma unroll
        for (int d = 0; d < DL; ++d) {
            float sP = wred(colP * psi_w2[d * HID + c]);
            psiv[d] = __shfl(sP, 0) * (1.0f / NPAIR) + psi_b2[d];
            float sF = wred(colF * phi_w2[d * HID + c]);
            phiv[d] = __shfl(sF, 0) * (1.0f / NPART) + phi_b2[d];
        }

        int j = lane;
        float a = rho_b0[j];
        const float* wr = rho_w0 + j * (2 * DL);
#pragma unroll
        for (int d = 0; d < DL; ++d)
            a += phiv[d] * wr[d] + psiv[d] * wr[DL + d];
        float cuspb = s_cusp[2 * blr] + s_cusp[2 * blr + 1];
        float cv = gelu_sig(a) * rho_w1[j];
        cv = wred(cv);
        if (j == 0) out[bg + blr] = cv + rho_b1[0] + cuspb;
    }
}

extern "C" void kernel_launch(void* const* d_in, const int* in_sizes, int n_in,
                              void* d_out, int out_size, void* d_ws, size_t ws_size,
                              hipStream_t stream) {
    const float* x      = (const float*)d_in[0];
    const float* phi_w0 = (const float*)d_in[1];
    const float* phi_b0 = (const float*)d_in[2];
    const float* phi_w1 = (const float*)d_in[3];
    const float* phi_b1 = (const float*)d_in[4];
    const float* phi_w2 = (const float*)d_in[5];
    const float* phi_b2 = (const float*)d_in[6];
    const float* psi_w0 = (const float*)d_in[7];
    const float* psi_b0 = (const float*)d_in[8];
    const float* psi_w1 = (const float*)d_in[9];
    const float* psi_b1 = (const float*)d_in[10];
    const float* psi_w2 = (const float*)d_in[11];
    const float* psi_b2 = (const float*)d_in[12];
    const float* rho_w0 = (const float*)d_in[13];
    const float* rho_b0 = (const float*)d_in[14];
    const float* rho_w1 = (const float*)d_in[15];
    const float* rho_b1 = (const float*)d_in[16];

    jastrow_mfma7<<<B_TOT / GB, 256, 0, stream>>>(
        x,
        phi_w0, phi_b0, phi_w1, phi_b1, phi_w2, phi_b2,
        psi_w0, psi_b0, psi_w1, psi_b1, psi_w2, psi_b2,
        rho_w0, rho_b0, rho_w1, rho_b1,
        (float*)d_out);
}